// Round 7
// baseline (19.827 us; speedup 1.0000x reference)
//
#include <hip/hip_runtime.h>

// EdgeNetwork: messages[e,i] = sum_j relu(edges[e,:] @ W[:, i*32+j] + b[i*32+j]) * states[e,j]
// M = 65536 rows, F=16, D=32.
//
// Round-7: back to the R3 operand mapping -- per n (16 per wave), one bf16 MFMA
// 32x32x16 computes D_n[j][e] = sum_f W[f][n*32+j] * edges[e][f]
// (A = W-slice in LDS, B = edges in regs; lane owns edge e = lane&31,
//  acc reg r owns j = (r&3)+8*(r>>2)+4*(lane>>5)).
// states[e][j] is then LANE-LOCAL (s[16] regs, loaded once, coalesced) -- this
// removes R5/R6's 4 states-broadcast ds_reads per iter, which made the kernel
// LDS-pipe-bound (~8.3 us floor; occupancy raise in R6 was null => pipe-bound).
// Loop LDS is now 1 ds_read_b128 per iter.
// R3's two defects fixed: per-iter shfl_xor -> batched 16 shuffles AFTER the
// loop (no lgkm serialization in-loop); per-iter bias-C broadcasts -> prep
// kernel writes a bias_nonzero flag; zero-C fast path when bias==0 (this
// problem), staged-bias slow path kept for generality.

typedef __attribute__((ext_vector_type(8))) short short8;
typedef __attribute__((ext_vector_type(16))) float f32x16;

#define WS_BYTES 36872   // 32768 W-frags (bf16) + 4096 bias C-frags (f32) + 4 flag

__device__ __forceinline__ unsigned short f2bf(float x) {
    union { float f; unsigned u; } v; v.f = x;
    return (unsigned short)((v.u + 0x7FFFu + ((v.u >> 16) & 1u)) >> 16);  // RNE
}

// ---- prep: W -> bf16 A-frag order, bias -> f32 C-frag order, bias_nz flag ----
// wf[((n*64 + l)*8 + t)] = bf16(W[f][n*32+j]), l = j + (f>>3)*32, t = f&7
// bf[n*32 + h*16 + r]    = bias[n*32 + (r&3) + 8*(r>>2) + 4*h]
// flag @36864            = OR of all bias bits
__global__ __launch_bounds__(256)
void edgenet_prep(const float* __restrict__ W, const float* __restrict__ bias,
                  void* __restrict__ ws)
{
    const int b = blockIdx.x;
    if (b < 68) {
        const int idx = b * 256 + threadIdx.x;        // 0..17407
        unsigned short* wf = (unsigned short*)ws;
        float* bf = (float*)((char*)ws + 32768);
        if (idx < 16384) {
            const int f = idx >> 10, c = idx & 1023, n = c >> 5, j = c & 31;
            wf[((n << 6) + j + ((f >> 3) << 5)) * 8 + (f & 7)] = f2bf(W[idx]);
        } else {
            const int t = idx - 16384;                // 0..1023
            const int r = t & 15, hh = (t >> 4) & 1, n = t >> 5;
            bf[t] = bias[(n << 5) + (r & 3) + ((r >> 2) << 3) + (hh << 2)];
        }
    } else {
        // flag block: OR-reduce the 1024 bias words
        const unsigned* ub = (const unsigned*)bias;
        unsigned v = 0;
        for (int i = threadIdx.x; i < 1024; i += 256) v |= ub[i];
        #pragma unroll
        for (int off = 32; off >= 1; off >>= 1) v |= __shfl_xor(v, off);
        __shared__ unsigned tmp[4];
        if ((threadIdx.x & 63) == 0) tmp[threadIdx.x >> 6] = v;
        __syncthreads();
        if (threadIdx.x == 0)
            *(unsigned*)((char*)ws + 36864) = tmp[0] | tmp[1] | tmp[2] | tmp[3];
    }
}

__global__ __launch_bounds__(512, 2)
void edgenet_main(const float* __restrict__ states,
                  const float* __restrict__ edges,
                  float* __restrict__ out,
                  const void* __restrict__ ws)
{
    __shared__ unsigned char LB[36864];          // [0,32768) W frags; [32768,) bias frags
    unsigned short* Wlds = (unsigned short*)LB;
    const float* Blds = (const float*)(LB + 32768);

    const int tid  = threadIdx.x;
    const int wave = tid >> 6;
    const int lane = tid & 63;
    const int ecol = lane & 31;                  // edge within tile (MFMA D column)
    const int h    = lane >> 5;
    const int tile  = blockIdx.x * 4 + (wave >> 1);   // 512 blocks * 4 = 2048 tiles
    const int nbase = (wave & 1) << 4;                // 0 or 16
    const long long row = (long long)tile * 32 + ecol;

    // ---- prefetch this lane's edges + states (hide HBM under staging) ----
    const float* ep = edges + row * 16 + h * 8;
    const float4 ev0 = *reinterpret_cast<const float4*>(ep);
    const float4 ev1 = *reinterpret_cast<const float4*>(ep + 4);
    const float* sp = states + row * 32 + h * 4;      // j_r = (r&3) + 8*(r>>2) + 4h
    const float4 sv0 = *reinterpret_cast<const float4*>(sp);
    const float4 sv1 = *reinterpret_cast<const float4*>(sp + 8);
    const float4 sv2 = *reinterpret_cast<const float4*>(sp + 16);
    const float4 sv3 = *reinterpret_cast<const float4*>(sp + 24);

    // ---- stage ws -> LDS: linear float4 copy (2304 chunks = 4*512 + 256) ----
    {
        const float4* g = (const float4*)ws;
        float4* l4 = (float4*)LB;
        #pragma unroll
        for (int i = 0; i < 4; ++i) l4[i * 512 + tid] = g[i * 512 + tid];
        if (tid < 256) l4[2048 + tid] = g[2048 + tid];
    }
    const unsigned bias_nz = *(const unsigned*)((const char*)ws + 36864);
    __syncthreads();

    // ---- B fragment: B[k=h*8+t][col=ecol] = edges[row][h*8+t] ----
    short8 bfrag;
    bfrag[0] = (short)f2bf(ev0.x); bfrag[1] = (short)f2bf(ev0.y);
    bfrag[2] = (short)f2bf(ev0.z); bfrag[3] = (short)f2bf(ev0.w);
    bfrag[4] = (short)f2bf(ev1.x); bfrag[5] = (short)f2bf(ev1.y);
    bfrag[6] = (short)f2bf(ev1.z); bfrag[7] = (short)f2bf(ev1.w);

    // s[r] = states[row][(r&3) + 8*(r>>2) + 4h]  (aligned with acc reg r)
    const float s[16] = {sv0.x, sv0.y, sv0.z, sv0.w,
                         sv1.x, sv1.y, sv1.z, sv1.w,
                         sv2.x, sv2.y, sv2.z, sv2.w,
                         sv3.x, sv3.y, sv3.z, sv3.w};

    const unsigned short* wl = &Wlds[(((unsigned)nbase << 6) + (unsigned)lane) << 3];
    const float* bb = &Blds[(nbase << 5) + (h << 4)];

    float pn[16];

    if (!bias_nz) {
        // ---- fast path: C = 0, loop LDS = 1 ds_read_b128 per iter ----
        f32x16 z;
        #pragma unroll
        for (int r = 0; r < 16; ++r) z[r] = 0.f;
        #pragma unroll
        for (int i = 0; i < 16; ++i) {
            const short8 afrag = *reinterpret_cast<const short8*>(wl + i * 512);
            const f32x16 acc = __builtin_amdgcn_mfma_f32_32x32x16_bf16(afrag, bfrag, z, 0, 0, 0);
            float p0 = 0.f, p1 = 0.f, p2 = 0.f, p3 = 0.f;
            #pragma unroll
            for (int r = 0; r < 16; r += 4) {
                p0 = fmaf(fmaxf(acc[r+0], 0.f), s[r+0], p0);
                p1 = fmaf(fmaxf(acc[r+1], 0.f), s[r+1], p1);
                p2 = fmaf(fmaxf(acc[r+2], 0.f), s[r+2], p2);
                p3 = fmaf(fmaxf(acc[r+3], 0.f), s[r+3], p3);
            }
            pn[i] = (p0 + p1) + (p2 + p3);
        }
    } else {
        // ---- general path: bias via MFMA C-operand (broadcast ds_reads) ----
        #pragma unroll
        for (int i = 0; i < 16; ++i) {
            f32x16 acc;
            #pragma unroll
            for (int r = 0; r < 16; ++r) acc[r] = bb[i * 32 + r];
            const short8 afrag = *reinterpret_cast<const short8*>(wl + i * 512);
            acc = __builtin_amdgcn_mfma_f32_32x32x16_bf16(afrag, bfrag, acc, 0, 0, 0);
            float p0 = 0.f, p1 = 0.f, p2 = 0.f, p3 = 0.f;
            #pragma unroll
            for (int r = 0; r < 16; r += 4) {
                p0 = fmaf(fmaxf(acc[r+0], 0.f), s[r+0], p0);
                p1 = fmaf(fmaxf(acc[r+1], 0.f), s[r+1], p1);
                p2 = fmaf(fmaxf(acc[r+2], 0.f), s[r+2], p2);
                p3 = fmaf(fmaxf(acc[r+3], 0.f), s[r+3], p3);
            }
            pn[i] = (p0 + p1) + (p2 + p3);
        }
    }

    // ---- batched cross-half combine: 16 back-to-back shuffles, no in-loop lgkm ----
    #pragma unroll
    for (int i = 0; i < 16; ++i) pn[i] += __shfl_xor(pn[i], 32);

    // ---- store: h==0 lanes write n=nbase+0..7, h==1 write nbase+8..15 ----
    float* op = out + row * 32 + nbase + h * 8;
    if (h == 0) {
        *reinterpret_cast<float4*>(op)     = make_float4(pn[0], pn[1], pn[2], pn[3]);
        *reinterpret_cast<float4*>(op + 4) = make_float4(pn[4], pn[5], pn[6], pn[7]);
    } else {
        *reinterpret_cast<float4*>(op)     = make_float4(pn[8],  pn[9],  pn[10], pn[11]);
        *reinterpret_cast<float4*>(op + 4) = make_float4(pn[12], pn[13], pn[14], pn[15]);
    }
}

// ---- fallback (ws too small): round-3 kernel (measured 20.9 us, always-bias) ----
__global__ __launch_bounds__(512, 2)
void edgenet_fallback(const float* __restrict__ states, const float* __restrict__ edges,
                      const float* __restrict__ W, const float* __restrict__ bias,
                      float* __restrict__ out)
{
    __shared__ unsigned short Wlds[16384];
    __shared__ float Blds[1024];
    const int tid  = threadIdx.x;
    const int wave = tid >> 6;
    const int lane = tid & 63;
    const int ecol = lane & 31;
    const int h    = lane >> 5;
    const int tile  = blockIdx.x * 4 + (wave >> 1);
    const int nbase = (wave & 1) << 4;
    const long long row = (long long)tile * 32 + ecol;

    const float* ep = edges + row * 16 + h * 8;
    const float4 ev0 = *reinterpret_cast<const float4*>(ep);
    const float4 ev1 = *reinterpret_cast<const float4*>(ep + 4);
    const float* sp = states + row * 32 + h * 4;
    const float4 sv0 = *reinterpret_cast<const float4*>(sp);
    const float4 sv1 = *reinterpret_cast<const float4*>(sp + 8);
    const float4 sv2 = *reinterpret_cast<const float4*>(sp + 16);
    const float4 sv3 = *reinterpret_cast<const float4*>(sp + 24);

    #pragma unroll
    for (int it = 0; it < 32; ++it) {
        int m = it * 512 + tid;
        int f = m >> 10, c = m & 1023, nn = c >> 5, j = c & 31;
        Wlds[((nn << 6) + j + ((f >> 3) << 5)) * 8 + (f & 7)] = f2bf(W[m]);
    }
    {
        int i0 = tid;
        int r = i0 & 15, hh = (i0 >> 4) & 1, nn = i0 >> 5;
        Blds[i0] = bias[(nn << 5) + (r & 3) + ((r >> 2) << 3) + (hh << 2)];
        int i1 = tid + 512;
        r = i1 & 15; hh = (i1 >> 4) & 1; nn = i1 >> 5;
        Blds[i1] = bias[(nn << 5) + (r & 3) + ((r >> 2) << 3) + (hh << 2)];
    }
    __syncthreads();

    short8 bfrag;
    bfrag[0] = (short)f2bf(ev0.x); bfrag[1] = (short)f2bf(ev0.y);
    bfrag[2] = (short)f2bf(ev0.z); bfrag[3] = (short)f2bf(ev0.w);
    bfrag[4] = (short)f2bf(ev1.x); bfrag[5] = (short)f2bf(ev1.y);
    bfrag[6] = (short)f2bf(ev1.z); bfrag[7] = (short)f2bf(ev1.w);
    const float s[16] = {sv0.x, sv0.y, sv0.z, sv0.w,
                         sv1.x, sv1.y, sv1.z, sv1.w,
                         sv2.x, sv2.y, sv2.z, sv2.w,
                         sv3.x, sv3.y, sv3.z, sv3.w};
    const unsigned short* wl = &Wlds[(((unsigned)nbase << 6) + (unsigned)lane) << 3];
    const float* bb = &Blds[(nbase << 5) + (h << 4)];
    float pn[16];

    #pragma unroll
    for (int i = 0; i < 16; ++i) {
        f32x16 acc;
        #pragma unroll
        for (int r = 0; r < 16; ++r) acc[r] = bb[i * 32 + r];
        const short8 afrag = *reinterpret_cast<const short8*>(wl + i * 512);
        acc = __builtin_amdgcn_mfma_f32_32x32x16_bf16(afrag, bfrag, acc, 0, 0, 0);
        float p0 = 0.f, p1 = 0.f, p2 = 0.f, p3 = 0.f;
        #pragma unroll
        for (int r = 0; r < 16; r += 4) {
            p0 = fmaf(fmaxf(acc[r+0], 0.f), s[r+0], p0);
            p1 = fmaf(fmaxf(acc[r+1], 0.f), s[r+1], p1);
            p2 = fmaf(fmaxf(acc[r+2], 0.f), s[r+2], p2);
            p3 = fmaf(fmaxf(acc[r+3], 0.f), s[r+3], p3);
        }
        pn[i] = (p0 + p1) + (p2 + p3);
    }
    #pragma unroll
    for (int i = 0; i < 16; ++i) pn[i] += __shfl_xor(pn[i], 32);

    float* op = out + row * 32 + nbase + h * 8;
    if (h == 0) {
        *reinterpret_cast<float4*>(op)     = make_float4(pn[0], pn[1], pn[2], pn[3]);
        *reinterpret_cast<float4*>(op + 4) = make_float4(pn[4], pn[5], pn[6], pn[7]);
    } else {
        *reinterpret_cast<float4*>(op)     = make_float4(pn[8],  pn[9],  pn[10], pn[11]);
        *reinterpret_cast<float4*>(op + 4) = make_float4(pn[12], pn[13], pn[14], pn[15]);
    }
}

extern "C" void kernel_launch(void* const* d_in, const int* in_sizes, int n_in,
                              void* d_out, int out_size, void* d_ws, size_t ws_size,
                              hipStream_t stream) {
    (void)in_sizes; (void)n_in; (void)out_size;
    const float* states = (const float*)d_in[0];
    const float* edges  = (const float*)d_in[1];
    const float* W      = (const float*)d_in[2];
    const float* bias   = (const float*)d_in[3];
    float* out          = (float*)d_out;

    if (ws_size >= (size_t)WS_BYTES) {
        hipLaunchKernelGGL(edgenet_prep, dim3(69), dim3(256), 0, stream, W, bias, d_ws);
        hipLaunchKernelGGL(edgenet_main, dim3(512), dim3(512), 0, stream,
                           states, edges, out, d_ws);
    } else {
        hipLaunchKernelGGL(edgenet_fallback, dim3(512), dim3(512), 0, stream,
                           states, edges, W, bias, out);
    }
}

// Round 8
// 16.044 us; speedup vs baseline: 1.2357x; 1.2357x over previous
//
#include <hip/hip_runtime.h>

// EdgeNetwork: messages[e,i] = sum_j relu(edges[e,:] @ W[:, i*32+j] + b[i*32+j]) * states[e,j]
// M = 65536 rows, F=16, D=32.
//
// Round-8: SINGLE kernel (R3..R7 evidence: three different inner loops all pin
// at ~19.5us -> cost is not the loop; eliminate the prep node + inter-kernel
// drain, and make in-kernel staging cheap).
// Mapping (R7, proven): per n (16 per wave), one bf16 MFMA 32x32x16 computes
// D_n[j][e] = sum_f W[f][n*32+j] * edges[e][f]; lane owns edge e = lane&31,
// acc reg r owns j = (r&3)+8*(r>>2)+4*(lane>>5); states lane-local in regs;
// loop LDS = 1 ds_read_b128/iter; shuffles batched after the loop.
// Staging (new, cheap): thread gathers W[0..15][c] for c = tid, tid+512
// (16 coalesced dword loads each), packs to bf16 via round-half-up
// (bits+0x8000, 5 VALU/pair), writes 2x ds_write_b128 per c in A-frag order.
// Bias: staged to C-frag order; zero-bias fast path via __ballot + LDS OR.

typedef __attribute__((ext_vector_type(8))) short short8;
typedef __attribute__((ext_vector_type(16))) float f32x16;

__device__ __forceinline__ unsigned short f2bf(float x) {
    union { float f; unsigned u; } v; v.f = x;
    return (unsigned short)((v.u + 0x7FFFu + ((v.u >> 16) & 1u)) >> 16);  // RNE
}

__global__ __launch_bounds__(512, 2)
void edgenet_kernel(const float* __restrict__ states,
                    const float* __restrict__ edges,
                    const float* __restrict__ W,
                    const float* __restrict__ bias,
                    float* __restrict__ out)
{
    // Wlds chunk (n*64 + l) [16B each]: A[row=l&31][k=(l>>5)*8+t] = W[f=(l>>5)*8+t][n*32+(l&31)]
    __shared__ unsigned short Wlds[16384];   // 32 KB, A-frag order bf16
    __shared__ float Blds[1024];             // C-frag order bias
    __shared__ unsigned long long nzv[8];

    const int tid  = threadIdx.x;
    const int wave = tid >> 6;
    const int lane = tid & 63;
    const int ecol = lane & 31;              // edge within tile (MFMA D column)
    const int h    = lane >> 5;
    const int tile  = blockIdx.x * 4 + (wave >> 1);   // 512 blocks * 4 = 2048 tiles
    const int nbase = (wave & 1) << 4;                // 0 or 16
    const long long row = (long long)tile * 32 + ecol;

    // ---- prefetch this lane's edges + states (issue before staging) ----
    const float* ep = edges + row * 16 + h * 8;
    const float4 ev0 = *reinterpret_cast<const float4*>(ep);
    const float4 ev1 = *reinterpret_cast<const float4*>(ep + 4);
    const float* sp = states + row * 32 + h * 4;      // j_r = (r&3) + 8*(r>>2) + 4h
    const float4 sv0 = *reinterpret_cast<const float4*>(sp);
    const float4 sv1 = *reinterpret_cast<const float4*>(sp + 8);
    const float4 sv2 = *reinterpret_cast<const float4*>(sp + 16);
    const float4 sv3 = *reinterpret_cast<const float4*>(sp + 24);

    // ---- stage W: c = tid, tid+512; 16 coalesced dword gathers (stride 1024),
    //      pack round-half-up bf16 pairs, 2x ds_write_b128 in A-frag order ----
    {
        int4* w4 = reinterpret_cast<int4*>(Wlds);
        #pragma unroll
        for (int cx = 0; cx < 2; ++cx) {
            const int c = tid + (cx << 9);
            const int n = c >> 5, j = c & 31;
            const unsigned* wc = reinterpret_cast<const unsigned*>(W) + c;
            unsigned b[16];
            #pragma unroll
            for (int f = 0; f < 16; ++f) b[f] = wc[f << 10] + 0x8000u;  // round-half-up
            int4 lohalf, hihalf;
            lohalf.x = (int)((b[1]  & 0xFFFF0000u) | (b[0]  >> 16));
            lohalf.y = (int)((b[3]  & 0xFFFF0000u) | (b[2]  >> 16));
            lohalf.z = (int)((b[5]  & 0xFFFF0000u) | (b[4]  >> 16));
            lohalf.w = (int)((b[7]  & 0xFFFF0000u) | (b[6]  >> 16));
            hihalf.x = (int)((b[9]  & 0xFFFF0000u) | (b[8]  >> 16));
            hihalf.y = (int)((b[11] & 0xFFFF0000u) | (b[10] >> 16));
            hihalf.z = (int)((b[13] & 0xFFFF0000u) | (b[12] >> 16));
            hihalf.w = (int)((b[15] & 0xFFFF0000u) | (b[14] >> 16));
            w4[(n << 6) + j]      = lohalf;   // l = j       (f 0..7)
            w4[(n << 6) + j + 32] = hihalf;   // l = j + 32  (f 8..15)
        }
    }

    // ---- stage bias (C-frag order) + zero-detect ----
    {
        const int i0 = tid;
        int r = i0 & 15, hh = (i0 >> 4) & 1, nn = i0 >> 5;
        const float b0 = bias[(nn << 5) + (r & 3) + ((r >> 2) << 3) + (hh << 2)];
        const int i1 = tid + 512;
        r = i1 & 15; hh = (i1 >> 4) & 1; nn = i1 >> 5;
        const float b1 = bias[(nn << 5) + (r & 3) + ((r >> 2) << 3) + (hh << 2)];
        Blds[i0] = b0;
        Blds[i1] = b1;
        const unsigned nz = __float_as_uint(b0) | __float_as_uint(b1);
        const unsigned long long bal = __ballot(nz != 0u);
        if (lane == 0) nzv[wave] = bal;
    }
    __syncthreads();
    const bool bias_zero =
        ((nzv[0] | nzv[1] | nzv[2] | nzv[3] | nzv[4] | nzv[5] | nzv[6] | nzv[7]) == 0ULL);

    // ---- B fragment: B[k=h*8+t][col=ecol] = edges[row][h*8+t] ----
    short8 bfrag;
    bfrag[0] = (short)f2bf(ev0.x); bfrag[1] = (short)f2bf(ev0.y);
    bfrag[2] = (short)f2bf(ev0.z); bfrag[3] = (short)f2bf(ev0.w);
    bfrag[4] = (short)f2bf(ev1.x); bfrag[5] = (short)f2bf(ev1.y);
    bfrag[6] = (short)f2bf(ev1.z); bfrag[7] = (short)f2bf(ev1.w);

    // s[r] = states[row][(r&3) + 8*(r>>2) + 4h]  (aligned with acc reg r)
    const float s[16] = {sv0.x, sv0.y, sv0.z, sv0.w,
                         sv1.x, sv1.y, sv1.z, sv1.w,
                         sv2.x, sv2.y, sv2.z, sv2.w,
                         sv3.x, sv3.y, sv3.z, sv3.w};

    const unsigned short* wl = &Wlds[(((unsigned)nbase << 6) + (unsigned)lane) << 3];
    const float* bb = &Blds[(nbase << 5) + (h << 4)];

    float pn[16];

    if (bias_zero) {
        // ---- fast path: C = 0, loop LDS = 1 ds_read_b128 per iter ----
        f32x16 z;
        #pragma unroll
        for (int r = 0; r < 16; ++r) z[r] = 0.f;
        #pragma unroll
        for (int i = 0; i < 16; ++i) {
            const short8 afrag = *reinterpret_cast<const short8*>(wl + i * 512);
            const f32x16 acc = __builtin_amdgcn_mfma_f32_32x32x16_bf16(afrag, bfrag, z, 0, 0, 0);
            float p0 = 0.f, p1 = 0.f, p2 = 0.f, p3 = 0.f;
            #pragma unroll
            for (int r = 0; r < 16; r += 4) {
                p0 = fmaf(fmaxf(acc[r+0], 0.f), s[r+0], p0);
                p1 = fmaf(fmaxf(acc[r+1], 0.f), s[r+1], p1);
                p2 = fmaf(fmaxf(acc[r+2], 0.f), s[r+2], p2);
                p3 = fmaf(fmaxf(acc[r+3], 0.f), s[r+3], p3);
            }
            pn[i] = (p0 + p1) + (p2 + p3);
        }
    } else {
        // ---- general path: bias via MFMA C-operand (broadcast ds_reads) ----
        #pragma unroll
        for (int i = 0; i < 16; ++i) {
            f32x16 acc;
            #pragma unroll
            for (int r = 0; r < 16; ++r) acc[r] = bb[i * 32 + r];
            const short8 afrag = *reinterpret_cast<const short8*>(wl + i * 512);
            acc = __builtin_amdgcn_mfma_f32_32x32x16_bf16(afrag, bfrag, acc, 0, 0, 0);
            float p0 = 0.f, p1 = 0.f, p2 = 0.f, p3 = 0.f;
            #pragma unroll
            for (int r = 0; r < 16; r += 4) {
                p0 = fmaf(fmaxf(acc[r+0], 0.f), s[r+0], p0);
                p1 = fmaf(fmaxf(acc[r+1], 0.f), s[r+1], p1);
                p2 = fmaf(fmaxf(acc[r+2], 0.f), s[r+2], p2);
                p3 = fmaf(fmaxf(acc[r+3], 0.f), s[r+3], p3);
            }
            pn[i] = (p0 + p1) + (p2 + p3);
        }
    }

    // ---- batched cross-half combine: 16 back-to-back shuffles ----
    #pragma unroll
    for (int i = 0; i < 16; ++i) pn[i] += __shfl_xor(pn[i], 32);

    // ---- store: h==0 lanes write n=nbase+0..7, h==1 write nbase+8..15 ----
    float* op = out + row * 32 + nbase + h * 8;
    if (h == 0) {
        *reinterpret_cast<float4*>(op)     = make_float4(pn[0], pn[1], pn[2], pn[3]);
        *reinterpret_cast<float4*>(op + 4) = make_float4(pn[4], pn[5], pn[6], pn[7]);
    } else {
        *reinterpret_cast<float4*>(op)     = make_float4(pn[8],  pn[9],  pn[10], pn[11]);
        *reinterpret_cast<float4*>(op + 4) = make_float4(pn[12], pn[13], pn[14], pn[15]);
    }
}

extern "C" void kernel_launch(void* const* d_in, const int* in_sizes, int n_in,
                              void* d_out, int out_size, void* d_ws, size_t ws_size,
                              hipStream_t stream) {
    (void)in_sizes; (void)n_in; (void)d_ws; (void)ws_size; (void)out_size;
    const float* states = (const float*)d_in[0];
    const float* edges  = (const float*)d_in[1];
    const float* W      = (const float*)d_in[2];
    const float* bias   = (const float*)d_in[3];
    float* out          = (float*)d_out;

    hipLaunchKernelGGL(edgenet_kernel, dim3(512), dim3(512), 0, stream,
                       states, edges, W, bias, out);
}